// Round 5
// baseline (651.094 us; speedup 1.0000x reference)
//
#include <hip/hip_runtime.h>
#include <hip/hip_cooperative_groups.h>
#include <math.h>

namespace cg = cooperative_groups;

// ---------------------------------------------------------------------------
// GATv2 2-layer GNN, fp32 in/out. N=50000, E=800000, F=128.
//   1. setup_coop_kernel (1 cooperative launch): zero deg + prep_w ->
//      count -> 3-phase scan -> scatter, grid.sync() between phases.
//      (replaces memset + 6 kernels; launch-overhead reduction)
//   2. GEMM (split-bf16 MFMA 3-term, in-kernel split -- r4's pre-split
//      path was a measured regression, reverted) -> bufA, bufB
//   3. aggregate v5 (16-lane groups, DPP-only per-edge reduce) -> bufC
//   4. GEMM bufC @ {Wl2,Wr2} ; aggregate -> d_out
// ---------------------------------------------------------------------------

typedef short bf16x8 __attribute__((ext_vector_type(8)));
typedef float f32x4 __attribute__((ext_vector_type(4)));

// ---------------------------------------------------------------------------
// Fused setup: phases separated by grid.sync().
//   0: deg[i]=0 (grid-stride); top 32 blocks also split W -> wt
//   1: count degrees (atomicAdd)
//   2: per-256-node chunk sums -> blockSums
//   3: block 0: exclusive scan of blockSums -> blockOffs, total -> row_ptr[N]
//   4: apply local scan + chunk offset -> row_ptr, writeidx
//   5: scatter edges -> csr_src
// ---------------------------------------------------------------------------
__global__ __launch_bounds__(256) void setup_coop_kernel(
    const int* __restrict__ src, const int* __restrict__ dst, int E, int N, int nBlk,
    const float* __restrict__ W0, const float* __restrict__ W1,
    const float* __restrict__ W2, const float* __restrict__ W3, short* __restrict__ wt,
    int* __restrict__ deg, int* __restrict__ row_ptr, int* __restrict__ writeidx,
    int* __restrict__ csr_src, int* __restrict__ blockSums, int* __restrict__ blockOffs) {
    cg::grid_group grid = cg::this_grid();
    __shared__ int wsum[4];
    __shared__ int sTotal;
    int tid = threadIdx.x, lane = tid & 63, wid = tid >> 6;
    int gsize = gridDim.x * 256;
    int gtid = blockIdx.x * 256 + tid;

    // --- phase 0: zero deg; high 32 blocks also prep W ---
    for (int i = gtid; i < N; i += gsize) deg[i] = 0;
    if (blockIdx.x >= gridDim.x - 32) {
        int b = blockIdx.x - (gridDim.x - 32);
        int mat = b >> 3, chunk = b & 7;
        const float* W = (mat == 0) ? W0 : (mat == 1) ? W1 : (mat == 2) ? W2 : W3;
        short* hi = wt + (size_t)mat * 2 * 16384;
        short* lo = hi + 16384;
        int i0 = chunk * 2048;
        for (int i = i0 + tid; i < i0 + 2048; i += 256) {
            int k = i >> 7, n = i & 127;
            float x = W[i];
            unsigned u = __float_as_uint(x);
            unsigned hu = u & 0xFFFF0000u;
            float lf = x - __uint_as_float(hu);
            hi[n * 128 + k] = (short)(hu >> 16);
            lo[n * 128 + k] = (short)(__float_as_uint(lf) >> 16);
        }
    }
    grid.sync();

    // --- phase 1: degree count ---
    for (int i = gtid; i < E; i += gsize) atomicAdd(&deg[dst[i]], 1);
    grid.sync();

    // --- phase 2: per-chunk (256 nodes) sums ---
    for (int c = blockIdx.x; c < nBlk; c += gridDim.x) {
        int idx = c * 256 + tid;
        int v = (idx < N) ? deg[idx] : 0;
        #pragma unroll
        for (int off = 32; off > 0; off >>= 1) v += __shfl_xor(v, off);
        if (lane == 0) wsum[wid] = v;
        __syncthreads();
        if (tid == 0) blockSums[c] = wsum[0] + wsum[1] + wsum[2] + wsum[3];
        __syncthreads();
    }
    grid.sync();

    // --- phase 3: single-block exclusive scan of blockSums ---
    if (blockIdx.x == 0) {
        int carry = 0;
        for (int base = 0; base < nBlk; base += 256) {
            int idx = base + tid;
            int v = (idx < nBlk) ? blockSums[idx] : 0;
            int incl = v;
            #pragma unroll
            for (int off = 1; off < 64; off <<= 1) {
                int t = __shfl_up(incl, off);
                if (lane >= off) incl += t;
            }
            if (lane == 63) wsum[wid] = incl;
            __syncthreads();
            if (tid == 0) {
                int a = wsum[0], b = wsum[1], c2 = wsum[2], d = wsum[3];
                wsum[0] = 0; wsum[1] = a; wsum[2] = a + b; wsum[3] = a + b + c2;
                sTotal = a + b + c2 + d;
            }
            __syncthreads();
            if (idx < nBlk) blockOffs[idx] = carry + wsum[wid] + (incl - v);
            carry += sTotal;
            __syncthreads();
        }
        if (tid == 0) row_ptr[N] = carry;
    }
    grid.sync();

    // --- phase 4: apply local scan + chunk offset ---
    for (int c = blockIdx.x; c < nBlk; c += gridDim.x) {
        int idx = c * 256 + tid;
        int v = (idx < N) ? deg[idx] : 0;
        int incl = v;
        #pragma unroll
        for (int off = 1; off < 64; off <<= 1) {
            int t = __shfl_up(incl, off);
            if (lane >= off) incl += t;
        }
        if (lane == 63) wsum[wid] = incl;
        __syncthreads();
        int woff = 0;
        #pragma unroll
        for (int w = 0; w < 4; ++w) woff += (w < wid) ? wsum[w] : 0;
        int excl = blockOffs[c] + woff + (incl - v);
        if (idx < N) { row_ptr[idx] = excl; writeidx[idx] = excl; }
        __syncthreads();
    }
    grid.sync();

    // --- phase 5: scatter edges ---
    for (int i = gtid; i < E; i += gsize) {
        int d = dst[i];
        int pos = atomicAdd(&writeidx[d], 1);
        csr_src[pos] = src[i];
    }
}

// ---------------------------------------------------------------------------
// Split-bf16 MFMA GEMM: out = X @ W + b (in-kernel hi/lo split).
// Block: 256 thr, tile 128(M) x 128(N), K=128 in 4 chunks of 32.
// Wave w owns ALL 128 rows x cols [w*32, w*32+32): 8 m-tiles x 2 n-tiles.
// ---------------------------------------------------------------------------
__global__ __launch_bounds__(256) void gemm_mfma_dual_kernel(
    const float* __restrict__ X, const short* __restrict__ wt,
    const float* __restrict__ b0, float* __restrict__ out0,
    const float* __restrict__ b1, float* __restrict__ out1,
    int Nrows) {
    const short* WTh = wt + (size_t)blockIdx.y * 2 * 16384;
    const short* WTl = WTh + 16384;
    const float* bias = blockIdx.y ? b1 : b0;
    float* out = blockIdx.y ? out1 : out0;

    __shared__ __attribute__((aligned(16))) short Ahi[128][40];
    __shared__ __attribute__((aligned(16))) short Alo[128][40];

    int tid = threadIdx.x;
    int w = tid >> 6, lane = tid & 63, q = lane >> 4, tr = lane & 15;
    int m0 = blockIdx.x * 128;
    int n0 = w * 32;

    f32x4 acc[8][2];
    #pragma unroll
    for (int a = 0; a < 8; ++a)
        #pragma unroll
        for (int b = 0; b < 2; ++b) acc[a][b] = (f32x4){0.f, 0.f, 0.f, 0.f};

    int srow = tid >> 3;        // 0..31
    int scol = (tid & 7) * 4;   // 0..28

    for (int kc = 0; kc < 128; kc += 32) {
        #pragma unroll
        for (int pass = 0; pass < 4; ++pass) {
            int r = srow + pass * 32;
            int gr = m0 + r; if (gr >= Nrows) gr = Nrows - 1;  // stores guarded later
            float4 v = *(const float4*)&X[(size_t)gr * 128 + kc + scol];
            float vv[4] = {v.x, v.y, v.z, v.w};
            short h[4], l[4];
            #pragma unroll
            for (int j = 0; j < 4; ++j) {
                unsigned u = __float_as_uint(vv[j]);
                unsigned hu = u & 0xFFFF0000u;
                float lf = vv[j] - __uint_as_float(hu);
                h[j] = (short)(hu >> 16);
                l[j] = (short)(__float_as_uint(lf) >> 16);
            }
            *(short4*)&Ahi[r][scol] = make_short4(h[0], h[1], h[2], h[3]);
            *(short4*)&Alo[r][scol] = make_short4(l[0], l[1], l[2], l[3]);
        }
        __syncthreads();

        bf16x8 bh[2], bl[2];
        #pragma unroll
        for (int nt = 0; nt < 2; ++nt) {
            size_t boff = (size_t)(n0 + nt * 16 + tr) * 128 + kc + q * 8;
            bh[nt] = *(const bf16x8*)&WTh[boff];
            bl[nt] = *(const bf16x8*)&WTl[boff];
        }

        #pragma unroll
        for (int mt = 0; mt < 8; ++mt) {
            bf16x8 ah = *(const bf16x8*)&Ahi[mt * 16 + tr][q * 8];
            bf16x8 al = *(const bf16x8*)&Alo[mt * 16 + tr][q * 8];
            #pragma unroll
            for (int nt = 0; nt < 2; ++nt) {
                acc[mt][nt] = __builtin_amdgcn_mfma_f32_16x16x32_bf16(ah, bh[nt], acc[mt][nt], 0, 0, 0);
                acc[mt][nt] = __builtin_amdgcn_mfma_f32_16x16x32_bf16(ah, bl[nt], acc[mt][nt], 0, 0, 0);
                acc[mt][nt] = __builtin_amdgcn_mfma_f32_16x16x32_bf16(al, bh[nt], acc[mt][nt], 0, 0, 0);
            }
        }
        __syncthreads();
    }

    #pragma unroll
    for (int nt = 0; nt < 2; ++nt) {
        float bv = bias[n0 + nt * 16 + tr];
        #pragma unroll
        for (int mt = 0; mt < 8; ++mt) {
            #pragma unroll
            for (int r = 0; r < 4; ++r) {
                int row = m0 + mt * 16 + q * 4 + r;
                if (row < Nrows)
                    out[(size_t)row * 128 + n0 + nt * 16 + tr] = acc[mt][nt][r] + bv;
            }
        }
    }
}

// ---------------------------------------------------------------------------
// Aggregation v5: 16-lane groups, 4 edges in flight per wave.
// Lane layout: qid = lane>>4 (edge group 0..3), qlane = lane&15.
// Per-edge score reduce: 4 shfl_xor levels, all intra-16 (DPP path).
// Cross-group (xor16/32) reduction hoisted to once per node.
// ---------------------------------------------------------------------------
__global__ __launch_bounds__(256) void gat_aggregate_kernel(
    const float* __restrict__ xl, const float* __restrict__ xr,
    const float* __restrict__ att, const float* __restrict__ bias,
    const int* __restrict__ row_ptr, const int* __restrict__ csr_src,
    float* __restrict__ out, int N, int applyRelu) {
    int wid = threadIdx.x >> 6;      // 0..3 -> node within block
    int lane = threadIdx.x & 63;
    int qlane = lane & 15;
    int qid = lane >> 4;
    int node = blockIdx.x * 4 + wid;
    if (node >= N) return;

    const float4* xl4 = (const float4*)xl;
    float4 xrL = ((const float4*)xr)[(size_t)node * 32 + qlane];
    float4 xrH = ((const float4*)xr)[(size_t)node * 32 + 16 + qlane];
    float4 atL = ((const float4*)att)[qlane];
    float4 atH = ((const float4*)att)[16 + qlane];

    int beg = row_ptr[node];
    int end = row_ptr[node + 1];

    float dsum = 0.f;
    float4 accL = {0.f, 0.f, 0.f, 0.f};
    float4 accH = {0.f, 0.f, 0.f, 0.f};

    for (int cbase = beg; cbase < end; cbase += 64) {
        int cnt = end - cbase;
        if (cnt > 64) cnt = 64;
        int myidx = (lane < cnt) ? csr_src[cbase + lane] : 0;  // coalesced
        int nq = (cnt + 3) >> 2;                               // quads of 4 edges

        for (int g = 0; g < nq; ++g) {
            int eidx = 4 * g + qid;
            int s = __shfl(myidx, eidx);
            float4 vL = xl4[(s << 5) + qlane];
            float4 vH = xl4[(s << 5) + 16 + qlane];

            float t, p;
            t = vL.x + xrL.x; t = t > 0.f ? t : 0.2f * t; p = t * atL.x;
            t = vL.y + xrL.y; t = t > 0.f ? t : 0.2f * t; p = fmaf(t, atL.y, p);
            t = vL.z + xrL.z; t = t > 0.f ? t : 0.2f * t; p = fmaf(t, atL.z, p);
            t = vL.w + xrL.w; t = t > 0.f ? t : 0.2f * t; p = fmaf(t, atL.w, p);
            t = vH.x + xrH.x; t = t > 0.f ? t : 0.2f * t; p = fmaf(t, atH.x, p);
            t = vH.y + xrH.y; t = t > 0.f ? t : 0.2f * t; p = fmaf(t, atH.y, p);
            t = vH.z + xrH.z; t = t > 0.f ? t : 0.2f * t; p = fmaf(t, atH.z, p);
            t = vH.w + xrH.w; t = t > 0.f ? t : 0.2f * t; p = fmaf(t, atH.w, p);

            p += __shfl_xor(p, 1);
            p += __shfl_xor(p, 2);
            p += __shfl_xor(p, 4);
            p += __shfl_xor(p, 8);

            float e = (eidx < cnt) ? __expf(p) : 0.f;
            dsum += e;
            accL.x = fmaf(e, vL.x, accL.x);
            accL.y = fmaf(e, vL.y, accL.y);
            accL.z = fmaf(e, vL.z, accL.z);
            accL.w = fmaf(e, vL.w, accL.w);
            accH.x = fmaf(e, vH.x, accH.x);
            accH.y = fmaf(e, vH.y, accH.y);
            accH.z = fmaf(e, vH.z, accH.z);
            accH.w = fmaf(e, vH.w, accH.w);
        }
    }

    #pragma unroll
    for (int off = 16; off <= 32; off <<= 1) {
        dsum += __shfl_xor(dsum, off);
        accL.x += __shfl_xor(accL.x, off);
        accL.y += __shfl_xor(accL.y, off);
        accL.z += __shfl_xor(accL.z, off);
        accL.w += __shfl_xor(accL.w, off);
        accH.x += __shfl_xor(accH.x, off);
        accH.y += __shfl_xor(accH.y, off);
        accH.z += __shfl_xor(accH.z, off);
        accH.w += __shfl_xor(accH.w, off);
    }

    float inv = dsum > 0.f ? 1.f / dsum : 0.f;
    float4 bvL = ((const float4*)bias)[qlane];
    float4 bvH = ((const float4*)bias)[16 + qlane];
    float4 oL, oH;
    oL.x = accL.x * inv + bvL.x; oL.y = accL.y * inv + bvL.y;
    oL.z = accL.z * inv + bvL.z; oL.w = accL.w * inv + bvL.w;
    oH.x = accH.x * inv + bvH.x; oH.y = accH.y * inv + bvH.y;
    oH.z = accH.z * inv + bvH.z; oH.w = accH.w * inv + bvH.w;
    if (applyRelu) {
        oL.x = fmaxf(oL.x, 0.f); oL.y = fmaxf(oL.y, 0.f);
        oL.z = fmaxf(oL.z, 0.f); oL.w = fmaxf(oL.w, 0.f);
        oH.x = fmaxf(oH.x, 0.f); oH.y = fmaxf(oH.y, 0.f);
        oH.z = fmaxf(oH.z, 0.f); oH.w = fmaxf(oH.w, 0.f);
    }
    if (lane < 16) {
        ((float4*)out)[(size_t)node * 32 + qlane] = oL;
        ((float4*)out)[(size_t)node * 32 + 16 + qlane] = oH;
    }
}

// ---------------------------------------------------------------------------

extern "C" void kernel_launch(void* const* d_in, const int* in_sizes, int n_in,
                              void* d_out, int out_size, void* d_ws, size_t ws_size,
                              hipStream_t stream) {
    const float* x    = (const float*)d_in[0];
    const int* eidx   = (const int*)d_in[1];
    const float* Wl1  = (const float*)d_in[2];
    const float* bl1  = (const float*)d_in[3];
    const float* Wr1  = (const float*)d_in[4];
    const float* br1  = (const float*)d_in[5];
    const float* att1 = (const float*)d_in[6];
    const float* b1   = (const float*)d_in[7];
    const float* Wl2  = (const float*)d_in[8];
    const float* bl2  = (const float*)d_in[9];
    const float* Wr2  = (const float*)d_in[10];
    const float* br2  = (const float*)d_in[11];
    const float* att2 = (const float*)d_in[12];
    const float* b2   = (const float*)d_in[13];

    const int N = in_sizes[0] / 128;
    const int E = in_sizes[1] / 2;
    const int* src = eidx;
    const int* dst = eidx + E;

    const int nBlk = (N + 255) / 256;

    // workspace layout
    size_t NF = (size_t)N * 128;
    float* bufA = (float*)d_ws;          // xl
    float* bufB = bufA + NF;             // xr
    float* bufC = bufB + NF;             // h
    int* deg       = (int*)(bufC + NF);  // [N]
    int* row_ptr   = deg + N;            // [N+1]
    int* writeidx  = row_ptr + (N + 1);  // [N]
    int* csr_src   = writeidx + N;       // [E]
    int* blockSums = csr_src + E;        // [nBlk]
    int* blockOffs = blockSums + nBlk;   // [nBlk]
    short* wt      = (short*)(blockOffs + nBlk);  // 4 matrices x (hi+lo) x 16384

    float* outF = (float*)d_out;

    // --- fused setup (1 cooperative launch replaces memset + 6 kernels) ---
    {
        int En = E, Nn = N, nB = nBlk;
        void* cargs[] = {
            (void*)&src, (void*)&dst, (void*)&En, (void*)&Nn, (void*)&nB,
            (void*)&Wl1, (void*)&Wr1, (void*)&Wl2, (void*)&Wr2, (void*)&wt,
            (void*)&deg, (void*)&row_ptr, (void*)&writeidx, (void*)&csr_src,
            (void*)&blockSums, (void*)&blockOffs
        };
        hipLaunchCooperativeKernel((void*)setup_coop_kernel, dim3(512), dim3(256),
                                   cargs, 0, stream);
    }

    dim3 gemmGrid((N + 127) / 128, 2);
    dim3 aggGrid((N + 3) / 4);

    // --- layer 1 ---
    gemm_mfma_dual_kernel<<<gemmGrid, 256, 0, stream>>>(x, wt, bl1, bufA, br1, bufB, N);
    gat_aggregate_kernel<<<aggGrid, 256, 0, stream>>>(bufA, bufB, att1, b1, row_ptr, csr_src,
                                                      bufC, N, 1);
    // --- layer 2 ---
    gemm_mfma_dual_kernel<<<gemmGrid, 256, 0, stream>>>(bufC, wt + 2 * 2 * 16384, bl2, bufA,
                                                        br2, bufB, N);
    gat_aggregate_kernel<<<aggGrid, 256, 0, stream>>>(bufA, bufB, att2, b2, row_ptr, csr_src,
                                                      outF, N, 0);
}

// Round 6
// 488.527 us; speedup vs baseline: 1.3328x; 1.3328x over previous
//
#include <hip/hip_runtime.h>
#include <math.h>

// ---------------------------------------------------------------------------
// GATv2 2-layer GNN, fp32 in/out. N=50000, E=800000, F=128.
// 8 dispatches (was 11): memset -> count+prep_w (fused) -> full-scan (1 blk)
//   -> scatter -> GEMM1 -> agg1 -> GEMM2 -> agg2
// GEMM: M=64 x N=256 dual-output tile (both Wl and Wr in one block):
//   every X row staged exactly ONCE (was twice), 8 ds_read + 48 MFMA per
//   wave-chunk, acc[4][4] = 64 VGPR. grid.sync fusion falsified in r5
//   (70us/sync); split-operand staging falsified in r4; SW-pipeline in r1/r2.
// agg v5 (16-lane groups, DPP-only reduce): stable 61us latency floor.
// ---------------------------------------------------------------------------

typedef short bf16x8 __attribute__((ext_vector_type(8)));
typedef float f32x4 __attribute__((ext_vector_type(4)));

// ---------------------------------------------------------------------------
// count degrees (blocks [0,nCnt)) + split W -> bf16 hi/lo [n][k] (32 blocks)
// ---------------------------------------------------------------------------
__global__ __launch_bounds__(256) void count_prep_kernel(
    const int* __restrict__ dst, int* __restrict__ deg, int E, int nCnt,
    const float* __restrict__ W0, const float* __restrict__ W1,
    const float* __restrict__ W2, const float* __restrict__ W3,
    short* __restrict__ wt) {
    if ((int)blockIdx.x < nCnt) {
        int i = blockIdx.x * 256 + threadIdx.x;
        if (i < E) atomicAdd(&deg[dst[i]], 1);
    } else {
        int b = blockIdx.x - nCnt;           // 0..31
        int mat = b >> 3, chunk = b & 7;
        const float* W = (mat == 0) ? W0 : (mat == 1) ? W1 : (mat == 2) ? W2 : W3;
        short* hi = wt + (size_t)mat * 2 * 16384;
        short* lo = hi + 16384;
        int i0 = chunk * 2048;
        for (int i = i0 + threadIdx.x; i < i0 + 2048; i += 256) {
            int k = i >> 7, n = i & 127;
            float x = W[i];
            unsigned u = __float_as_uint(x);
            unsigned hu = u & 0xFFFF0000u;
            float lf = x - __uint_as_float(hu);
            hi[n * 128 + k] = (short)(hu >> 16);
            lo[n * 128 + k] = (short)(__float_as_uint(lf) >> 16);
        }
    }
}

// ---------------------------------------------------------------------------
// Single-block full exclusive scan: deg[0..n) -> row_ptr[0..n], writeidx.
// 256 threads, strips of 256 with carried prefix. Replaces 3 kernels.
// ---------------------------------------------------------------------------
__global__ __launch_bounds__(256) void scan_full_kernel(
    const int* __restrict__ deg, int* __restrict__ row_ptr,
    int* __restrict__ writeidx, int n) {
    __shared__ int wsum[4];
    int tid = threadIdx.x, lane = tid & 63, wid = tid >> 6;
    int carry = 0;
    for (int base = 0; base < n; base += 256) {
        int idx = base + tid;
        int v = (idx < n) ? deg[idx] : 0;
        int incl = v;
        #pragma unroll
        for (int off = 1; off < 64; off <<= 1) {
            int t = __shfl_up(incl, off);
            if (lane >= off) incl += t;
        }
        if (lane == 63) wsum[wid] = incl;
        __syncthreads();
        int woff = 0;
        #pragma unroll
        for (int w = 0; w < 4; ++w) woff += (w < wid) ? wsum[w] : 0;
        int tot = wsum[0] + wsum[1] + wsum[2] + wsum[3];
        int excl = carry + woff + (incl - v);
        if (idx < n) { row_ptr[idx] = excl; writeidx[idx] = excl; }
        carry += tot;
        __syncthreads();
    }
    if (tid == 0) row_ptr[n] = carry;
}

__global__ void scatter_edges_kernel(const int* __restrict__ src, const int* __restrict__ dst,
                                     int* __restrict__ writeidx, int* __restrict__ csr_src, int E) {
    int i = blockIdx.x * blockDim.x + threadIdx.x;
    if (i < E) {
        int d = dst[i];
        int pos = atomicAdd(&writeidx[d], 1);
        csr_src[pos] = src[i];
    }
}

// ---------------------------------------------------------------------------
// Split-bf16 MFMA GEMM, dual-output 64x256 tile: {out0,out1} = X @ {W0,W1} + b.
// Block: 256 thr, 64 rows, K=128 in 4 chunks of 32. Each wave owns all 64
// rows x 32 cols of BOTH output matrices: 4 m-tiles x (2 plane x 2 n-tile).
// X row staged exactly once grid-wide. wtL: [p][hi/lo][n][k] planes.
// ---------------------------------------------------------------------------
__global__ __launch_bounds__(256) void gemm_mfma_dual64_kernel(
    const float* __restrict__ X, const short* __restrict__ wtL,
    const float* __restrict__ b0, float* __restrict__ out0,
    const float* __restrict__ b1, float* __restrict__ out1,
    int Nrows) {
    __shared__ __attribute__((aligned(16))) short Ahi[64][40];
    __shared__ __attribute__((aligned(16))) short Alo[64][40];

    int tid = threadIdx.x;
    int w = tid >> 6, lane = tid & 63, q = lane >> 4, tr = lane & 15;
    int m0 = blockIdx.x * 64;
    int n0 = w * 32;

    f32x4 acc[4][4];   // [mt][p*2+nt]
    #pragma unroll
    for (int a = 0; a < 4; ++a)
        #pragma unroll
        for (int b = 0; b < 4; ++b) acc[a][b] = (f32x4){0.f, 0.f, 0.f, 0.f};

    int srow = tid >> 2;        // 0..63
    int scol = (tid & 3) * 8;   // 0,8,16,24

    for (int kc = 0; kc < 128; kc += 32) {
        // stage + split 64 rows x 32 k (one pass, 8 floats/thread)
        {
            int gr = m0 + srow; if (gr >= Nrows) gr = Nrows - 1;  // stores guarded later
            const float* xp = &X[(size_t)gr * 128 + kc + scol];
            float4 v0 = *(const float4*)xp;
            float4 v1 = *(const float4*)(xp + 4);
            float f[8] = {v0.x, v0.y, v0.z, v0.w, v1.x, v1.y, v1.z, v1.w};
            bf16x8 hv, lv;
            #pragma unroll
            for (int j = 0; j < 8; ++j) {
                unsigned u = __float_as_uint(f[j]);
                unsigned hu = u & 0xFFFF0000u;
                float lf = f[j] - __uint_as_float(hu);
                hv[j] = (short)(hu >> 16);
                lv[j] = (short)(__float_as_uint(lf) >> 16);
            }
            *(bf16x8*)&Ahi[srow][scol] = hv;
            *(bf16x8*)&Alo[srow][scol] = lv;
        }
        __syncthreads();

        // B fragments: 2 planes x 2 n-tiles x hi/lo (L2-resident)
        bf16x8 bh[4], bl[4];
        #pragma unroll
        for (int p = 0; p < 2; ++p) {
            const short* base = wtL + (size_t)p * 2 * 16384;
            #pragma unroll
            for (int nt = 0; nt < 2; ++nt) {
                size_t boff = (size_t)(n0 + nt * 16 + tr) * 128 + kc + q * 8;
                bh[p * 2 + nt] = *(const bf16x8*)&base[boff];
                bl[p * 2 + nt] = *(const bf16x8*)&base[16384 + boff];
            }
        }

        // A fragments from LDS, 4 m-tiles; 3-term split MFMA
        #pragma unroll
        for (int mt = 0; mt < 4; ++mt) {
            bf16x8 ah = *(const bf16x8*)&Ahi[mt * 16 + tr][q * 8];
            bf16x8 al = *(const bf16x8*)&Alo[mt * 16 + tr][q * 8];
            #pragma unroll
            for (int j = 0; j < 4; ++j) {
                acc[mt][j] = __builtin_amdgcn_mfma_f32_16x16x32_bf16(ah, bh[j], acc[mt][j], 0, 0, 0);
                acc[mt][j] = __builtin_amdgcn_mfma_f32_16x16x32_bf16(ah, bl[j], acc[mt][j], 0, 0, 0);
                acc[mt][j] = __builtin_amdgcn_mfma_f32_16x16x32_bf16(al, bh[j], acc[mt][j], 0, 0, 0);
            }
        }
        __syncthreads();
    }

    // epilogue: D layout col = tr, row = q*4 + r
    #pragma unroll
    for (int p = 0; p < 2; ++p) {
        const float* bias = p ? b1 : b0;
        float* out = p ? out1 : out0;
        #pragma unroll
        for (int nt = 0; nt < 2; ++nt) {
            float bv = bias[n0 + nt * 16 + tr];
            #pragma unroll
            for (int mt = 0; mt < 4; ++mt) {
                #pragma unroll
                for (int r = 0; r < 4; ++r) {
                    int row = m0 + mt * 16 + q * 4 + r;
                    if (row < Nrows)
                        out[(size_t)row * 128 + n0 + nt * 16 + tr] = acc[mt][p * 2 + nt][r] + bv;
                }
            }
        }
    }
}

// ---------------------------------------------------------------------------
// Aggregation v5: 16-lane groups, 4 edges in flight per wave.
// qid = lane>>4 (edge slot), qlane = lane&15. Per-edge reduce: 4 intra-16
// shfl_xor levels (DPP). Cross-group xor16/32 hoisted to once per node.
// ---------------------------------------------------------------------------
__global__ __launch_bounds__(256) void gat_aggregate_kernel(
    const float* __restrict__ xl, const float* __restrict__ xr,
    const float* __restrict__ att, const float* __restrict__ bias,
    const int* __restrict__ row_ptr, const int* __restrict__ csr_src,
    float* __restrict__ out, int N, int applyRelu) {
    int wid = threadIdx.x >> 6;      // 0..3 -> node within block
    int lane = threadIdx.x & 63;
    int qlane = lane & 15;
    int qid = lane >> 4;
    int node = blockIdx.x * 4 + wid;
    if (node >= N) return;

    const float4* xl4 = (const float4*)xl;
    float4 xrL = ((const float4*)xr)[(size_t)node * 32 + qlane];
    float4 xrH = ((const float4*)xr)[(size_t)node * 32 + 16 + qlane];
    float4 atL = ((const float4*)att)[qlane];
    float4 atH = ((const float4*)att)[16 + qlane];

    int beg = row_ptr[node];
    int end = row_ptr[node + 1];

    float dsum = 0.f;
    float4 accL = {0.f, 0.f, 0.f, 0.f};
    float4 accH = {0.f, 0.f, 0.f, 0.f};

    for (int cbase = beg; cbase < end; cbase += 64) {
        int cnt = end - cbase;
        if (cnt > 64) cnt = 64;
        int myidx = (lane < cnt) ? csr_src[cbase + lane] : 0;  // coalesced
        int nq = (cnt + 3) >> 2;                               // quads of 4 edges

        for (int g = 0; g < nq; ++g) {
            int eidx = 4 * g + qid;
            int s = __shfl(myidx, eidx);
            float4 vL = xl4[(s << 5) + qlane];
            float4 vH = xl4[(s << 5) + 16 + qlane];

            float t, p;
            t = vL.x + xrL.x; t = t > 0.f ? t : 0.2f * t; p = t * atL.x;
            t = vL.y + xrL.y; t = t > 0.f ? t : 0.2f * t; p = fmaf(t, atL.y, p);
            t = vL.z + xrL.z; t = t > 0.f ? t : 0.2f * t; p = fmaf(t, atL.z, p);
            t = vL.w + xrL.w; t = t > 0.f ? t : 0.2f * t; p = fmaf(t, atL.w, p);
            t = vH.x + xrH.x; t = t > 0.f ? t : 0.2f * t; p = fmaf(t, atH.x, p);
            t = vH.y + xrH.y; t = t > 0.f ? t : 0.2f * t; p = fmaf(t, atH.y, p);
            t = vH.z + xrH.z; t = t > 0.f ? t : 0.2f * t; p = fmaf(t, atH.z, p);
            t = vH.w + xrH.w; t = t > 0.f ? t : 0.2f * t; p = fmaf(t, atH.w, p);

            p += __shfl_xor(p, 1);
            p += __shfl_xor(p, 2);
            p += __shfl_xor(p, 4);
            p += __shfl_xor(p, 8);

            float e = (eidx < cnt) ? __expf(p) : 0.f;
            dsum += e;
            accL.x = fmaf(e, vL.x, accL.x);
            accL.y = fmaf(e, vL.y, accL.y);
            accL.z = fmaf(e, vL.z, accL.z);
            accL.w = fmaf(e, vL.w, accL.w);
            accH.x = fmaf(e, vH.x, accH.x);
            accH.y = fmaf(e, vH.y, accH.y);
            accH.z = fmaf(e, vH.z, accH.z);
            accH.w = fmaf(e, vH.w, accH.w);
        }
    }

    #pragma unroll
    for (int off = 16; off <= 32; off <<= 1) {
        dsum += __shfl_xor(dsum, off);
        accL.x += __shfl_xor(accL.x, off);
        accL.y += __shfl_xor(accL.y, off);
        accL.z += __shfl_xor(accL.z, off);
        accL.w += __shfl_xor(accL.w, off);
        accH.x += __shfl_xor(accH.x, off);
        accH.y += __shfl_xor(accH.y, off);
        accH.z += __shfl_xor(accH.z, off);
        accH.w += __shfl_xor(accH.w, off);
    }

    float inv = dsum > 0.f ? 1.f / dsum : 0.f;
    float4 bvL = ((const float4*)bias)[qlane];
    float4 bvH = ((const float4*)bias)[16 + qlane];
    float4 oL, oH;
    oL.x = accL.x * inv + bvL.x; oL.y = accL.y * inv + bvL.y;
    oL.z = accL.z * inv + bvL.z; oL.w = accL.w * inv + bvL.w;
    oH.x = accH.x * inv + bvH.x; oH.y = accH.y * inv + bvH.y;
    oH.z = accH.z * inv + bvH.z; oH.w = accH.w * inv + bvH.w;
    if (applyRelu) {
        oL.x = fmaxf(oL.x, 0.f); oL.y = fmaxf(oL.y, 0.f);
        oL.z = fmaxf(oL.z, 0.f); oL.w = fmaxf(oL.w, 0.f);
        oH.x = fmaxf(oH.x, 0.f); oH.y = fmaxf(oH.y, 0.f);
        oH.z = fmaxf(oH.z, 0.f); oH.w = fmaxf(oH.w, 0.f);
    }
    if (lane < 16) {
        ((float4*)out)[(size_t)node * 32 + qlane] = oL;
        ((float4*)out)[(size_t)node * 32 + 16 + qlane] = oH;
    }
}

// ---------------------------------------------------------------------------

extern "C" void kernel_launch(void* const* d_in, const int* in_sizes, int n_in,
                              void* d_out, int out_size, void* d_ws, size_t ws_size,
                              hipStream_t stream) {
    const float* x    = (const float*)d_in[0];
    const int* eidx   = (const int*)d_in[1];
    const float* Wl1  = (const float*)d_in[2];
    const float* bl1  = (const float*)d_in[3];
    const float* Wr1  = (const float*)d_in[4];
    const float* br1  = (const float*)d_in[5];
    const float* att1 = (const float*)d_in[6];
    const float* b1   = (const float*)d_in[7];
    const float* Wl2  = (const float*)d_in[8];
    const float* bl2  = (const float*)d_in[9];
    const float* Wr2  = (const float*)d_in[10];
    const float* br2  = (const float*)d_in[11];
    const float* att2 = (const float*)d_in[12];
    const float* b2   = (const float*)d_in[13];

    const int N = in_sizes[0] / 128;
    const int E = in_sizes[1] / 2;
    const int* src = eidx;
    const int* dst = eidx + E;

    // workspace layout
    size_t NF = (size_t)N * 128;
    float* bufA = (float*)d_ws;          // xl
    float* bufB = bufA + NF;             // xr
    float* bufC = bufB + NF;             // h
    int* deg       = (int*)(bufC + NF);  // [N]
    int* row_ptr   = deg + N;            // [N+1]
    int* writeidx  = row_ptr + (N + 1);  // [N]
    int* csr_src   = writeidx + N;       // [E]
    short* wt      = (short*)(csr_src + E);  // 4 matrices x (hi+lo) x 16384

    float* outF = (float*)d_out;

    // --- CSR build + W prep (4 dispatches) ---
    const int nCnt = (E + 255) / 256;
    hipMemsetAsync(deg, 0, (size_t)N * sizeof(int), stream);
    count_prep_kernel<<<nCnt + 32, 256, 0, stream>>>(dst, deg, E, nCnt,
                                                     Wl1, Wr1, Wl2, Wr2, wt);
    scan_full_kernel<<<1, 256, 0, stream>>>(deg, row_ptr, writeidx, N);
    scatter_edges_kernel<<<nCnt, 256, 0, stream>>>(src, dst, writeidx, csr_src, E);

    dim3 gemmGrid((N + 63) / 64);
    dim3 aggGrid((N + 3) / 4);

    // --- layer 1 ---
    gemm_mfma_dual64_kernel<<<gemmGrid, 256, 0, stream>>>(x, wt, bl1, bufA, br1, bufB, N);
    gat_aggregate_kernel<<<aggGrid, 256, 0, stream>>>(bufA, bufB, att1, b1, row_ptr, csr_src,
                                                      bufC, N, 1);
    // --- layer 2 ---
    gemm_mfma_dual64_kernel<<<gemmGrid, 256, 0, stream>>>(bufC, wt + 2 * 2 * 16384, bl2, bufA,
                                                          br2, bufB, N);
    gat_aggregate_kernel<<<aggGrid, 256, 0, stream>>>(bufA, bufB, att2, b2, row_ptr, csr_src,
                                                      outF, N, 0);
}

// Round 7
// 383.378 us; speedup vs baseline: 1.6983x; 1.2743x over previous
//
#include <hip/hip_runtime.h>
#include <math.h>

// ---------------------------------------------------------------------------
// GATv2 2-layer GNN, fp32 in/out. N=50000, E=800000, F=128.
// 10 dispatches: memset -> count+prep_w -> scan(3, hierarchical; the 1-block
//   full scan was a 115us regression in r6) -> scatter -> GEMM1 -> agg1 ->
//   GEMM2 -> agg2
// GEMM: one-barrier dual-output 64x256 tile. Full 64x128 A-tile staged in
//   one shot (8 float4 loads/thread all in flight), split to bf16 hi/lo LDS
//   (stride 136 = 2-way max bank aliasing, free), ONE __syncthreads, then
//   pure LDS+MFMA phase (192 MFMA + 32 ds_read_b128 / wave).
// agg v5 (16-lane groups, DPP-only reduce): stable 61us latency floor.
// Falsified: grid.sync fusion (r5, 70us/sync), split-operand GEMM (r4),
//   agg SW-pipeline (r1/r2), 1-block scan (r6).
// ---------------------------------------------------------------------------

typedef short bf16x8 __attribute__((ext_vector_type(8)));
typedef float f32x4 __attribute__((ext_vector_type(4)));

// ---------------------------------------------------------------------------
// count degrees (blocks [0,nCnt)) + split W -> bf16 hi/lo [n][k] (32 blocks)
// ---------------------------------------------------------------------------
__global__ __launch_bounds__(256) void count_prep_kernel(
    const int* __restrict__ dst, int* __restrict__ deg, int E, int nCnt,
    const float* __restrict__ W0, const float* __restrict__ W1,
    const float* __restrict__ W2, const float* __restrict__ W3,
    short* __restrict__ wt) {
    if ((int)blockIdx.x < nCnt) {
        int i = blockIdx.x * 256 + threadIdx.x;
        if (i < E) atomicAdd(&deg[dst[i]], 1);
    } else {
        int b = blockIdx.x - nCnt;           // 0..31
        int mat = b >> 3, chunk = b & 7;
        const float* W = (mat == 0) ? W0 : (mat == 1) ? W1 : (mat == 2) ? W2 : W3;
        short* hi = wt + (size_t)mat * 2 * 16384;
        short* lo = hi + 16384;
        int i0 = chunk * 2048;
        for (int i = i0 + threadIdx.x; i < i0 + 2048; i += 256) {
            int k = i >> 7, n = i & 127;
            float x = W[i];
            unsigned u = __float_as_uint(x);
            unsigned hu = u & 0xFFFF0000u;
            float lf = x - __uint_as_float(hu);
            hi[n * 128 + k] = (short)(hu >> 16);
            lo[n * 128 + k] = (short)(__float_as_uint(lf) >> 16);
        }
    }
}

// --- hierarchical scan: pass 1 -- per-block (256 nodes) sums ---
__global__ __launch_bounds__(256) void scan_blocksum_kernel(const int* __restrict__ deg,
                                                            int* __restrict__ blockSums, int n) {
    __shared__ int wsum[4];
    int tid = threadIdx.x;
    int idx = blockIdx.x * 256 + tid;
    int v = (idx < n) ? deg[idx] : 0;
    int lane = tid & 63, wid = tid >> 6;
    #pragma unroll
    for (int off = 32; off > 0; off >>= 1) v += __shfl_xor(v, off);
    if (lane == 0) wsum[wid] = v;
    __syncthreads();
    if (tid == 0) blockSums[blockIdx.x] = wsum[0] + wsum[1] + wsum[2] + wsum[3];
}

// --- pass 2 -- single-block exclusive scan of block sums ---
__global__ __launch_bounds__(256) void scan_sums_kernel(int* __restrict__ blockSums,
                                                        int* __restrict__ blockOffs,
                                                        int* __restrict__ totalOut, int n) {
    __shared__ int wsumExcl[4];
    __shared__ int sTotal;
    int tid = threadIdx.x, lane = tid & 63, wid = tid >> 6;
    int carry = 0;
    for (int base = 0; base < n; base += 256) {
        int idx = base + tid;
        int v = (idx < n) ? blockSums[idx] : 0;
        int incl = v;
        #pragma unroll
        for (int off = 1; off < 64; off <<= 1) {
            int t = __shfl_up(incl, off);
            if (lane >= off) incl += t;
        }
        if (lane == 63) wsumExcl[wid] = incl;
        __syncthreads();
        if (tid == 0) {
            int a = wsumExcl[0], b = wsumExcl[1], c = wsumExcl[2], d = wsumExcl[3];
            wsumExcl[0] = 0; wsumExcl[1] = a; wsumExcl[2] = a + b; wsumExcl[3] = a + b + c;
            sTotal = a + b + c + d;
        }
        __syncthreads();
        if (idx < n) blockOffs[idx] = carry + wsumExcl[wid] + (incl - v);
        carry += sTotal;
        __syncthreads();
    }
    if (tid == 0) *totalOut = carry;
}

// --- pass 3 -- local scan + block offset -> row_ptr / writeidx ---
__global__ __launch_bounds__(256) void scan_apply_kernel(const int* __restrict__ deg,
                                                         const int* __restrict__ blockOffs,
                                                         int* __restrict__ row_ptr,
                                                         int* __restrict__ writeidx, int n) {
    __shared__ int wsum[4];
    int tid = threadIdx.x, lane = tid & 63, wid = tid >> 6;
    int idx = blockIdx.x * 256 + tid;
    int v = (idx < n) ? deg[idx] : 0;
    int incl = v;
    #pragma unroll
    for (int off = 1; off < 64; off <<= 1) {
        int t = __shfl_up(incl, off);
        if (lane >= off) incl += t;
    }
    if (lane == 63) wsum[wid] = incl;
    __syncthreads();
    int woff = 0;
    #pragma unroll
    for (int w = 0; w < 4; ++w) woff += (w < wid) ? wsum[w] : 0;
    int excl = blockOffs[blockIdx.x] + woff + (incl - v);
    if (idx < n) { row_ptr[idx] = excl; writeidx[idx] = excl; }
}

__global__ void scatter_edges_kernel(const int* __restrict__ src, const int* __restrict__ dst,
                                     int* __restrict__ writeidx, int* __restrict__ csr_src, int E) {
    int i = blockIdx.x * blockDim.x + threadIdx.x;
    if (i < E) {
        int d = dst[i];
        int pos = atomicAdd(&writeidx[d], 1);
        csr_src[pos] = src[i];
    }
}

// ---------------------------------------------------------------------------
// One-barrier split-bf16 MFMA GEMM, dual-output 64x256 tile:
//   {out0,out1} = X @ {W0,W1} + b.  wtL: [p][hi/lo][n][k] planes.
// Phase 1: stage full 64x128 A-tile (8 float4/thread, all loads in flight),
//   split -> Ahi/Alo LDS (stride 136 shorts: bank aliasing <=2-way, free).
// ONE __syncthreads.
// Phase 2: 4 K-chunks of pure compute: B frags from L2, A frags via
//   ds_read_b128, 48 MFMA per wave per chunk.
// ---------------------------------------------------------------------------
#define LDK 136
__global__ __launch_bounds__(256) void gemm_mfma_dual64_kernel(
    const float* __restrict__ X, const short* __restrict__ wtL,
    const float* __restrict__ b0, float* __restrict__ out0,
    const float* __restrict__ b1, float* __restrict__ out1,
    int Nrows) {
    __shared__ __attribute__((aligned(16))) short Ahi[64][LDK];
    __shared__ __attribute__((aligned(16))) short Alo[64][LDK];

    int tid = threadIdx.x;
    int w = tid >> 6, lane = tid & 63, q = lane >> 4, tr = lane & 15;
    int m0 = blockIdx.x * 64;
    int n0 = w * 32;

    // --- phase 1: stage whole A tile, one row per thread-quad ---
    {
        int srow = tid >> 2;            // 0..63
        int c0 = (tid & 3) * 32;        // 0,32,64,96
        int gr = m0 + srow; if (gr >= Nrows) gr = Nrows - 1;  // stores guarded later
        const float* xp = &X[(size_t)gr * 128 + c0];
        float4 v[8];
        #pragma unroll
        for (int j = 0; j < 8; ++j) v[j] = *(const float4*)(xp + j * 4);
        #pragma unroll
        for (int j = 0; j < 2; ++j) {
            bf16x8 hv, lv;
            #pragma unroll
            for (int k = 0; k < 2; ++k) {
                float4 vv = v[j * 2 + k];
                float f[4] = {vv.x, vv.y, vv.z, vv.w};
                #pragma unroll
                for (int e = 0; e < 4; ++e) {
                    unsigned u = __float_as_uint(f[e]);
                    unsigned hu = u & 0xFFFF0000u;
                    float lf = f[e] - __uint_as_float(hu);
                    hv[k * 4 + e] = (short)(hu >> 16);
                    lv[k * 4 + e] = (short)(__float_as_uint(lf) >> 16);
                }
            }
            *(bf16x8*)&Ahi[srow][c0 + j * 8] = hv;
            *(bf16x8*)&Alo[srow][c0 + j * 8] = lv;
        }
        #pragma unroll
        for (int j = 2; j < 4; ++j) {
            bf16x8 hv, lv;
            #pragma unroll
            for (int k = 0; k < 2; ++k) {
                float4 vv = v[j * 2 + k];
                float f[4] = {vv.x, vv.y, vv.z, vv.w};
                #pragma unroll
                for (int e = 0; e < 4; ++e) {
                    unsigned u = __float_as_uint(f[e]);
                    unsigned hu = u & 0xFFFF0000u;
                    float lf = f[e] - __uint_as_float(hu);
                    hv[k * 4 + e] = (short)(hu >> 16);
                    lv[k * 4 + e] = (short)(__float_as_uint(lf) >> 16);
                }
            }
            *(bf16x8*)&Ahi[srow][c0 + j * 8] = hv;
            *(bf16x8*)&Alo[srow][c0 + j * 8] = lv;
        }
    }
    __syncthreads();

    // --- phase 2: pure compute ---
    f32x4 acc[4][4];   // [mt][p*2+nt]
    #pragma unroll
    for (int a = 0; a < 4; ++a)
        #pragma unroll
        for (int b = 0; b < 4; ++b) acc[a][b] = (f32x4){0.f, 0.f, 0.f, 0.f};

    for (int kc = 0; kc < 128; kc += 32) {
        bf16x8 bh[4], bl[4];
        #pragma unroll
        for (int p = 0; p < 2; ++p) {
            const short* base = wtL + (size_t)p * 2 * 16384;
            #pragma unroll
            for (int nt = 0; nt < 2; ++nt) {
                size_t boff = (size_t)(n0 + nt * 16 + tr) * 128 + kc + q * 8;
                bh[p * 2 + nt] = *(const bf16x8*)&base[boff];
                bl[p * 2 + nt] = *(const bf16x8*)&base[16384 + boff];
            }
        }
        #pragma unroll
        for (int mt = 0; mt < 4; ++mt) {
            bf16x8 ah = *(const bf16x8*)&Ahi[mt * 16 + tr][kc + q * 8];
            bf16x8 al = *(const bf16x8*)&Alo[mt * 16 + tr][kc + q * 8];
            #pragma unroll
            for (int j = 0; j < 4; ++j) {
                acc[mt][j] = __builtin_amdgcn_mfma_f32_16x16x32_bf16(ah, bh[j], acc[mt][j], 0, 0, 0);
                acc[mt][j] = __builtin_amdgcn_mfma_f32_16x16x32_bf16(ah, bl[j], acc[mt][j], 0, 0, 0);
                acc[mt][j] = __builtin_amdgcn_mfma_f32_16x16x32_bf16(al, bh[j], acc[mt][j], 0, 0, 0);
            }
        }
    }

    // epilogue: D layout col = tr, row = q*4 + r
    #pragma unroll
    for (int p = 0; p < 2; ++p) {
        const float* bias = p ? b1 : b0;
        float* out = p ? out1 : out0;
        #pragma unroll
        for (int nt = 0; nt < 2; ++nt) {
            float bv = bias[n0 + nt * 16 + tr];
            #pragma unroll
            for (int mt = 0; mt < 4; ++mt) {
                #pragma unroll
                for (int r = 0; r < 4; ++r) {
                    int row = m0 + mt * 16 + q * 4 + r;
                    if (row < Nrows)
                        out[(size_t)row * 128 + n0 + nt * 16 + tr] = acc[mt][p * 2 + nt][r] + bv;
                }
            }
        }
    }
}
#undef LDK

// ---------------------------------------------------------------------------
// Aggregation v5: 16-lane groups, 4 edges in flight per wave.
// qid = lane>>4 (edge slot), qlane = lane&15. Per-edge reduce: 4 intra-16
// shfl_xor levels (DPP). Cross-group xor16/32 hoisted to once per node.
// ---------------------------------------------------------------------------
__global__ __launch_bounds__(256) void gat_aggregate_kernel(
    const float* __restrict__ xl, const float* __restrict__ xr,
    const float* __restrict__ att, const float* __restrict__ bias,
    const int* __restrict__ row_ptr, const int* __restrict__ csr_src,
    float* __restrict__ out, int N, int applyRelu) {
    int wid = threadIdx.x >> 6;      // 0..3 -> node within block
    int lane = threadIdx.x & 63;
    int qlane = lane & 15;
    int qid = lane >> 4;
    int node = blockIdx.x * 4 + wid;
    if (node >= N) return;

    const float4* xl4 = (const float4*)xl;
    float4 xrL = ((const float4*)xr)[(size_t)node * 32 + qlane];
    float4 xrH = ((const float4*)xr)[(size_t)node * 32 + 16 + qlane];
    float4 atL = ((const float4*)att)[qlane];
    float4 atH = ((const float4*)att)[16 + qlane];

    int beg = row_ptr[node];
    int end = row_ptr[node + 1];

    float dsum = 0.f;
    float4 accL = {0.f, 0.f, 0.f, 0.f};
    float4 accH = {0.f, 0.f, 0.f, 0.f};

    for (int cbase = beg; cbase < end; cbase += 64) {
        int cnt = end - cbase;
        if (cnt > 64) cnt = 64;
        int myidx = (lane < cnt) ? csr_src[cbase + lane] : 0;  // coalesced
        int nq = (cnt + 3) >> 2;                               // quads of 4 edges

        for (int g = 0; g < nq; ++g) {
            int eidx = 4 * g + qid;
            int s = __shfl(myidx, eidx);
            float4 vL = xl4[(s << 5) + qlane];
            float4 vH = xl4[(s << 5) + 16 + qlane];

            float t, p;
            t = vL.x + xrL.x; t = t > 0.f ? t : 0.2f * t; p = t * atL.x;
            t = vL.y + xrL.y; t = t > 0.f ? t : 0.2f * t; p = fmaf(t, atL.y, p);
            t = vL.z + xrL.z; t = t > 0.f ? t : 0.2f * t; p = fmaf(t, atL.z, p);
            t = vL.w + xrL.w; t = t > 0.f ? t : 0.2f * t; p = fmaf(t, atL.w, p);
            t = vH.x + xrH.x; t = t > 0.f ? t : 0.2f * t; p = fmaf(t, atH.x, p);
            t = vH.y + xrH.y; t = t > 0.f ? t : 0.2f * t; p = fmaf(t, atH.y, p);
            t = vH.z + xrH.z; t = t > 0.f ? t : 0.2f * t; p = fmaf(t, atH.z, p);
            t = vH.w + xrH.w; t = t > 0.f ? t : 0.2f * t; p = fmaf(t, atH.w, p);

            p += __shfl_xor(p, 1);
            p += __shfl_xor(p, 2);
            p += __shfl_xor(p, 4);
            p += __shfl_xor(p, 8);

            float e = (eidx < cnt) ? __expf(p) : 0.f;
            dsum += e;
            accL.x = fmaf(e, vL.x, accL.x);
            accL.y = fmaf(e, vL.y, accL.y);
            accL.z = fmaf(e, vL.z, accL.z);
            accL.w = fmaf(e, vL.w, accL.w);
            accH.x = fmaf(e, vH.x, accH.x);
            accH.y = fmaf(e, vH.y, accH.y);
            accH.z = fmaf(e, vH.z, accH.z);
            accH.w = fmaf(e, vH.w, accH.w);
        }
    }

    #pragma unroll
    for (int off = 16; off <= 32; off <<= 1) {
        dsum += __shfl_xor(dsum, off);
        accL.x += __shfl_xor(accL.x, off);
        accL.y += __shfl_xor(accL.y, off);
        accL.z += __shfl_xor(accL.z, off);
        accL.w += __shfl_xor(accL.w, off);
        accH.x += __shfl_xor(accH.x, off);
        accH.y += __shfl_xor(accH.y, off);
        accH.z += __shfl_xor(accH.z, off);
        accH.w += __shfl_xor(accH.w, off);
    }

    float inv = dsum > 0.f ? 1.f / dsum : 0.f;
    float4 bvL = ((const float4*)bias)[qlane];
    float4 bvH = ((const float4*)bias)[16 + qlane];
    float4 oL, oH;
    oL.x = accL.x * inv + bvL.x; oL.y = accL.y * inv + bvL.y;
    oL.z = accL.z * inv + bvL.z; oL.w = accL.w * inv + bvL.w;
    oH.x = accH.x * inv + bvH.x; oH.y = accH.y * inv + bvH.y;
    oH.z = accH.z * inv + bvH.z; oH.w = accH.w * inv + bvH.w;
    if (applyRelu) {
        oL.x = fmaxf(oL.x, 0.f); oL.y = fmaxf(oL.y, 0.f);
        oL.z = fmaxf(oL.z, 0.f); oL.w = fmaxf(oL.w, 0.f);
        oH.x = fmaxf(oH.x, 0.f); oH.y = fmaxf(oH.y, 0.f);
        oH.z = fmaxf(oH.z, 0.f); oH.w = fmaxf(oH.w, 0.f);
    }
    if (lane < 16) {
        ((float4*)out)[(size_t)node * 32 + qlane] = oL;
        ((float4*)out)[(size_t)node * 32 + 16 + qlane] = oH;
    }
}

// ---------------------------------------------------------------------------

extern "C" void kernel_launch(void* const* d_in, const int* in_sizes, int n_in,
                              void* d_out, int out_size, void* d_ws, size_t ws_size,
                              hipStream_t stream) {
    const float* x    = (const float*)d_in[0];
    const int* eidx   = (const int*)d_in[1];
    const float* Wl1  = (const float*)d_in[2];
    const float* bl1  = (const float*)d_in[3];
    const float* Wr1  = (const float*)d_in[4];
    const float* br1  = (const float*)d_in[5];
    const float* att1 = (const float*)d_in[6];
    const float* b1   = (const float*)d_in[7];
    const float* Wl2  = (const float*)d_in[8];
    const float* bl2  = (const float*)d_in[9];
    const float* Wr2  = (const float*)d_in[10];
    const float* br2  = (const float*)d_in[11];
    const float* att2 = (const float*)d_in[12];
    const float* b2   = (const float*)d_in[13];

    const int N = in_sizes[0] / 128;
    const int E = in_sizes[1] / 2;
    const int* src = eidx;
    const int* dst = eidx + E;

    const int nBlk = (N + 255) / 256;

    // workspace layout
    size_t NF = (size_t)N * 128;
    float* bufA = (float*)d_ws;          // xl
    float* bufB = bufA + NF;             // xr
    float* bufC = bufB + NF;             // h
    int* deg       = (int*)(bufC + NF);  // [N]
    int* row_ptr   = deg + N;            // [N+1]
    int* writeidx  = row_ptr + (N + 1);  // [N]
    int* csr_src   = writeidx + N;       // [E]
    int* blockSums = csr_src + E;        // [nBlk]
    int* blockOffs = blockSums + nBlk;   // [nBlk]
    short* wt      = (short*)(blockOffs + nBlk);  // 4 matrices x (hi+lo) x 16384

    float* outF = (float*)d_out;

    // --- CSR build + W prep ---
    const int nCnt = (E + 255) / 256;
    hipMemsetAsync(deg, 0, (size_t)N * sizeof(int), stream);
    count_prep_kernel<<<nCnt + 32, 256, 0, stream>>>(dst, deg, E, nCnt,
                                                     Wl1, Wr1, Wl2, Wr2, wt);
    scan_blocksum_kernel<<<nBlk, 256, 0, stream>>>(deg, blockSums, N);
    scan_sums_kernel<<<1, 256, 0, stream>>>(blockSums, blockOffs, &row_ptr[N], nBlk);
    scan_apply_kernel<<<nBlk, 256, 0, stream>>>(deg, blockOffs, row_ptr, writeidx, N);
    scatter_edges_kernel<<<nCnt, 256, 0, stream>>>(src, dst, writeidx, csr_src, E);

    dim3 gemmGrid((N + 63) / 64);
    dim3 aggGrid((N + 3) / 4);

    // --- layer 1 ---
    gemm_mfma_dual64_kernel<<<gemmGrid, 256, 0, stream>>>(x, wt, bl1, bufA, br1, bufB, N);
    gat_aggregate_kernel<<<aggGrid, 256, 0, stream>>>(bufA, bufB, att1, b1, row_ptr, csr_src,
                                                      bufC, N, 1);
    // --- layer 2 ---
    gemm_mfma_dual64_kernel<<<gemmGrid, 256, 0, stream>>>(bufC, wt + 2 * 2 * 16384, bl2, bufA,
                                                          br2, bufB, N);
    gat_aggregate_kernel<<<aggGrid, 256, 0, stream>>>(bufA, bufB, att2, b2, row_ptr, csr_src,
                                                      outF, N, 0);
}

// Round 8
// 337.211 us; speedup vs baseline: 1.9308x; 1.1369x over previous
//
#include <hip/hip_runtime.h>
#include <math.h>

// ---------------------------------------------------------------------------
// GATv2 2-layer GNN, fp32 in/out. N=50000, E=800000, F=128.
// 9 dispatches: memset -> count+prep_w -> scan_blocksum -> scan_apply2 ->
//   scatter -> GEMM1 -> agg1 -> GEMM2 -> agg2
// KEY CHANGE (r8): xl (the gathered message buffer) is stored as bf16 RNE.
//   Gather traffic halves (512->256 B/edge); L2 working set 25.6->12.8 MB.
//   xr, scores, softmax, accumulation, outputs remain fp32.
// GEMM: one-barrier dual-output 64x256 tile; xl plane written as bf16.
// agg v5 (16-lane groups, DPP-only reduce), 1x16B gather per edge-row.
// Falsified: grid.sync fusion (r5), split-operand GEMM (r4), agg SW-pipeline
//   (r1/r2), 1-block scan (r6).
// ---------------------------------------------------------------------------

typedef short bf16x8 __attribute__((ext_vector_type(8)));
typedef float f32x4 __attribute__((ext_vector_type(4)));

// ---------------------------------------------------------------------------
// count degrees (blocks [0,nCnt)) + split W -> bf16 hi/lo [n][k] (32 blocks)
// ---------------------------------------------------------------------------
__global__ __launch_bounds__(256) void count_prep_kernel(
    const int* __restrict__ dst, int* __restrict__ deg, int E, int nCnt,
    const float* __restrict__ W0, const float* __restrict__ W1,
    const float* __restrict__ W2, const float* __restrict__ W3,
    short* __restrict__ wt) {
    if ((int)blockIdx.x < nCnt) {
        int i = blockIdx.x * 256 + threadIdx.x;
        if (i < E) atomicAdd(&deg[dst[i]], 1);
    } else {
        int b = blockIdx.x - nCnt;           // 0..31
        int mat = b >> 3, chunk = b & 7;
        const float* W = (mat == 0) ? W0 : (mat == 1) ? W1 : (mat == 2) ? W2 : W3;
        short* hi = wt + (size_t)mat * 2 * 16384;
        short* lo = hi + 16384;
        int i0 = chunk * 2048;
        for (int i = i0 + threadIdx.x; i < i0 + 2048; i += 256) {
            int k = i >> 7, n = i & 127;
            float x = W[i];
            unsigned u = __float_as_uint(x);
            unsigned hu = u & 0xFFFF0000u;
            float lf = x - __uint_as_float(hu);
            hi[n * 128 + k] = (short)(hu >> 16);
            lo[n * 128 + k] = (short)(__float_as_uint(lf) >> 16);
        }
    }
}

// --- scan pass 1 -- per-block (256 nodes) sums ---
__global__ __launch_bounds__(256) void scan_blocksum_kernel(const int* __restrict__ deg,
                                                            int* __restrict__ blockSums, int n) {
    __shared__ int wsum[4];
    int tid = threadIdx.x;
    int idx = blockIdx.x * 256 + tid;
    int v = (idx < n) ? deg[idx] : 0;
    int lane = tid & 63, wid = tid >> 6;
    #pragma unroll
    for (int off = 32; off > 0; off >>= 1) v += __shfl_xor(v, off);
    if (lane == 0) wsum[wid] = v;
    __syncthreads();
    if (tid == 0) blockSums[blockIdx.x] = wsum[0] + wsum[1] + wsum[2] + wsum[3];
}

// --- scan pass 2 (fused): block offset by direct reduction over blockSums
//     (nBlk <= 256) + local scan -> row_ptr / writeidx. Block 0 writes total.
__global__ __launch_bounds__(256) void scan_apply2_kernel(
    const int* __restrict__ deg, const int* __restrict__ blockSums,
    int* __restrict__ row_ptr, int* __restrict__ writeidx, int n, int nBlk) {
    __shared__ int sPre[4], sAll[4], wsum[4];
    int tid = threadIdx.x, lane = tid & 63, wid = tid >> 6;

    int bsv = (tid < nBlk) ? blockSums[tid] : 0;
    int pre = (tid < (int)blockIdx.x) ? bsv : 0;
    int all = bsv;
    #pragma unroll
    for (int off = 32; off > 0; off >>= 1) {
        pre += __shfl_xor(pre, off);
        all += __shfl_xor(all, off);
    }
    if (lane == 0) { sPre[wid] = pre; sAll[wid] = all; }
    __syncthreads();
    int off0 = sPre[0] + sPre[1] + sPre[2] + sPre[3];
    int total = sAll[0] + sAll[1] + sAll[2] + sAll[3];

    int idx = blockIdx.x * 256 + tid;
    int v = (idx < n) ? deg[idx] : 0;
    int incl = v;
    #pragma unroll
    for (int off = 1; off < 64; off <<= 1) {
        int t = __shfl_up(incl, off);
        if (lane >= off) incl += t;
    }
    if (lane == 63) wsum[wid] = incl;
    __syncthreads();
    int woff = 0;
    #pragma unroll
    for (int w = 0; w < 4; ++w) woff += (w < wid) ? wsum[w] : 0;
    int excl = off0 + woff + (incl - v);
    if (idx < n) { row_ptr[idx] = excl; writeidx[idx] = excl; }
    if (blockIdx.x == 0 && tid == 0) row_ptr[n] = total;
}

__global__ void scatter_edges_kernel(const int* __restrict__ src, const int* __restrict__ dst,
                                     int* __restrict__ writeidx, int* __restrict__ csr_src, int E) {
    int i = blockIdx.x * blockDim.x + threadIdx.x;
    if (i < E) {
        int d = dst[i];
        int pos = atomicAdd(&writeidx[d], 1);
        csr_src[pos] = src[i];
    }
}

// ---------------------------------------------------------------------------
// One-barrier split-bf16 MFMA GEMM, dual-output 64x256 tile:
//   xl-plane (p=0) -> bf16 RNE [Nrows][128]; xr-plane (p=1) -> fp32.
// Phase 1: stage full 64x128 A-tile, split -> Ahi/Alo LDS (stride 136).
// ONE __syncthreads. Phase 2: 4 K-chunks pure compute (B frags from L2).
// ---------------------------------------------------------------------------
#define LDK 136
__global__ __launch_bounds__(256) void gemm_mfma_dual64_kernel(
    const float* __restrict__ X, const short* __restrict__ wtL,
    const float* __restrict__ b0, short* __restrict__ out0bf,
    const float* __restrict__ b1, float* __restrict__ out1,
    int Nrows) {
    __shared__ __attribute__((aligned(16))) short Ahi[64][LDK];
    __shared__ __attribute__((aligned(16))) short Alo[64][LDK];

    int tid = threadIdx.x;
    int w = tid >> 6, lane = tid & 63, q = lane >> 4, tr = lane & 15;
    int m0 = blockIdx.x * 64;
    int n0 = w * 32;

    // --- phase 1: stage whole A tile, one row per thread-quad ---
    {
        int srow = tid >> 2;            // 0..63
        int c0 = (tid & 3) * 32;        // 0,32,64,96
        int gr = m0 + srow; if (gr >= Nrows) gr = Nrows - 1;  // stores guarded later
        const float* xp = &X[(size_t)gr * 128 + c0];
        float4 v[8];
        #pragma unroll
        for (int j = 0; j < 8; ++j) v[j] = *(const float4*)(xp + j * 4);
        #pragma unroll
        for (int j = 0; j < 4; ++j) {
            bf16x8 hv, lv;
            #pragma unroll
            for (int k = 0; k < 2; ++k) {
                float4 vv = v[j * 2 + k];
                float f[4] = {vv.x, vv.y, vv.z, vv.w};
                #pragma unroll
                for (int e = 0; e < 4; ++e) {
                    unsigned u = __float_as_uint(f[e]);
                    unsigned hu = u & 0xFFFF0000u;
                    float lf = f[e] - __uint_as_float(hu);
                    hv[k * 4 + e] = (short)(hu >> 16);
                    lv[k * 4 + e] = (short)(__float_as_uint(lf) >> 16);
                }
            }
            *(bf16x8*)&Ahi[srow][c0 + j * 8] = hv;
            *(bf16x8*)&Alo[srow][c0 + j * 8] = lv;
        }
    }
    __syncthreads();

    // --- phase 2: pure compute ---
    f32x4 acc[4][4];   // [mt][p*2+nt]
    #pragma unroll
    for (int a = 0; a < 4; ++a)
        #pragma unroll
        for (int b = 0; b < 4; ++b) acc[a][b] = (f32x4){0.f, 0.f, 0.f, 0.f};

    for (int kc = 0; kc < 128; kc += 32) {
        bf16x8 bh[4], bl[4];
        #pragma unroll
        for (int p = 0; p < 2; ++p) {
            const short* base = wtL + (size_t)p * 2 * 16384;
            #pragma unroll
            for (int nt = 0; nt < 2; ++nt) {
                size_t boff = (size_t)(n0 + nt * 16 + tr) * 128 + kc + q * 8;
                bh[p * 2 + nt] = *(const bf16x8*)&base[boff];
                bl[p * 2 + nt] = *(const bf16x8*)&base[16384 + boff];
            }
        }
        #pragma unroll
        for (int mt = 0; mt < 4; ++mt) {
            bf16x8 ah = *(const bf16x8*)&Ahi[mt * 16 + tr][kc + q * 8];
            bf16x8 al = *(const bf16x8*)&Alo[mt * 16 + tr][kc + q * 8];
            #pragma unroll
            for (int j = 0; j < 4; ++j) {
                acc[mt][j] = __builtin_amdgcn_mfma_f32_16x16x32_bf16(ah, bh[j], acc[mt][j], 0, 0, 0);
                acc[mt][j] = __builtin_amdgcn_mfma_f32_16x16x32_bf16(ah, bl[j], acc[mt][j], 0, 0, 0);
                acc[mt][j] = __builtin_amdgcn_mfma_f32_16x16x32_bf16(al, bh[j], acc[mt][j], 0, 0, 0);
            }
        }
    }

    // epilogue: D layout col = tr, row = q*4 + r
    // p=0 (xl): bf16 RNE store. p=1 (xr): fp32 store.
    #pragma unroll
    for (int nt = 0; nt < 2; ++nt) {
        float bv0 = b0[n0 + nt * 16 + tr];
        float bv1 = b1[n0 + nt * 16 + tr];
        #pragma unroll
        for (int mt = 0; mt < 4; ++mt) {
            #pragma unroll
            for (int r = 0; r < 4; ++r) {
                int row = m0 + mt * 16 + q * 4 + r;
                if (row < Nrows) {
                    float v0 = acc[mt][nt][r] + bv0;
                    unsigned u = __float_as_uint(v0);
                    unsigned rb = (u + 0x7FFFu + ((u >> 16) & 1u)) >> 16;
                    out0bf[(size_t)row * 128 + n0 + nt * 16 + tr] = (short)rb;
                    out1[(size_t)row * 128 + n0 + nt * 16 + tr] = acc[mt][2 + nt][r] + bv1;
                }
            }
        }
    }
}
#undef LDK

// ---------------------------------------------------------------------------
// Aggregation v6: xl is bf16 [N][128]. 16-lane groups, 4 edges/wave.
// Lane qlane holds features [qlane*8, qlane*8+8): ONE 16B load per edge-row.
// Per-edge reduce: 4 intra-16 shfl_xor (DPP). xor16/32 hoisted per node.
// ---------------------------------------------------------------------------
__global__ __launch_bounds__(256) void gat_aggregate_kernel(
    const short* __restrict__ xl16, const float* __restrict__ xr,
    const float* __restrict__ att, const float* __restrict__ bias,
    const int* __restrict__ row_ptr, const int* __restrict__ csr_src,
    float* __restrict__ out, int N, int applyRelu) {
    int wid = threadIdx.x >> 6;      // 0..3 -> node within block
    int lane = threadIdx.x & 63;
    int qlane = lane & 15;
    int qid = lane >> 4;
    int node = blockIdx.x * 4 + wid;
    if (node >= N) return;

    const bf16x8* xlb = (const bf16x8*)xl16;   // row = 16 x bf16x8
    float4 xrA = ((const float4*)xr)[(size_t)node * 32 + qlane * 2];
    float4 xrB = ((const float4*)xr)[(size_t)node * 32 + qlane * 2 + 1];
    float4 atA = ((const float4*)att)[qlane * 2];
    float4 atB = ((const float4*)att)[qlane * 2 + 1];

    int beg = row_ptr[node];
    int end = row_ptr[node + 1];

    float dsum = 0.f;
    float4 accA = {0.f, 0.f, 0.f, 0.f};
    float4 accB = {0.f, 0.f, 0.f, 0.f};

    for (int cbase = beg; cbase < end; cbase += 64) {
        int cnt = end - cbase;
        if (cnt > 64) cnt = 64;
        int myidx = (lane < cnt) ? csr_src[cbase + lane] : 0;  // coalesced
        int nq = (cnt + 3) >> 2;                               // quads of 4 edges

        for (int g = 0; g < nq; ++g) {
            int eidx = 4 * g + qid;
            int s = __shfl(myidx, eidx);
            bf16x8 mv = xlb[((size_t)s << 4) + qlane];
            float4 vA, vB;
            vA.x = __uint_as_float(((unsigned)(unsigned short)mv[0]) << 16);
            vA.y = __uint_as_float(((unsigned)(unsigned short)mv[1]) << 16);
            vA.z = __uint_as_float(((unsigned)(unsigned short)mv[2]) << 16);
            vA.w = __uint_as_float(((unsigned)(unsigned short)mv[3]) << 16);
            vB.x = __uint_as_float(((unsigned)(unsigned short)mv[4]) << 16);
            vB.y = __uint_as_float(((unsigned)(unsigned short)mv[5]) << 16);
            vB.z = __uint_as_float(((unsigned)(unsigned short)mv[6]) << 16);
            vB.w = __uint_as_float(((unsigned)(unsigned short)mv[7]) << 16);

            float t, p;
            t = vA.x + xrA.x; t = t > 0.f ? t : 0.2f * t; p = t * atA.x;
            t = vA.y + xrA.y; t = t > 0.f ? t : 0.2f * t; p = fmaf(t, atA.y, p);
            t = vA.z + xrA.z; t = t > 0.f ? t : 0.2f * t; p = fmaf(t, atA.z, p);
            t = vA.w + xrA.w; t = t > 0.f ? t : 0.2f * t; p = fmaf(t, atA.w, p);
            t = vB.x + xrB.x; t = t > 0.f ? t : 0.2f * t; p = fmaf(t, atB.x, p);
            t = vB.y + xrB.y; t = t > 0.f ? t : 0.2f * t; p = fmaf(t, atB.y, p);
            t = vB.z + xrB.z; t = t > 0.f ? t : 0.2f * t; p = fmaf(t, atB.z, p);
            t = vB.w + xrB.w; t = t > 0.f ? t : 0.2f * t; p = fmaf(t, atB.w, p);

            p += __shfl_xor(p, 1);
            p += __shfl_xor(p, 2);
            p += __shfl_xor(p, 4);
            p += __shfl_xor(p, 8);

            float e = (eidx < cnt) ? __expf(p) : 0.f;
            dsum += e;
            accA.x = fmaf(e, vA.x, accA.x);
            accA.y = fmaf(e, vA.y, accA.y);
            accA.z = fmaf(e, vA.z, accA.z);
            accA.w = fmaf(e, vA.w, accA.w);
            accB.x = fmaf(e, vB.x, accB.x);
            accB.y = fmaf(e, vB.y, accB.y);
            accB.z = fmaf(e, vB.z, accB.z);
            accB.w = fmaf(e, vB.w, accB.w);
        }
    }

    #pragma unroll
    for (int off = 16; off <= 32; off <<= 1) {
        dsum += __shfl_xor(dsum, off);
        accA.x += __shfl_xor(accA.x, off);
        accA.y += __shfl_xor(accA.y, off);
        accA.z += __shfl_xor(accA.z, off);
        accA.w += __shfl_xor(accA.w, off);
        accB.x += __shfl_xor(accB.x, off);
        accB.y += __shfl_xor(accB.y, off);
        accB.z += __shfl_xor(accB.z, off);
        accB.w += __shfl_xor(accB.w, off);
    }

    float inv = dsum > 0.f ? 1.f / dsum : 0.f;
    float4 bvA = ((const float4*)bias)[qlane * 2];
    float4 bvB = ((const float4*)bias)[qlane * 2 + 1];
    float4 oA, oB;
    oA.x = accA.x * inv + bvA.x; oA.y = accA.y * inv + bvA.y;
    oA.z = accA.z * inv + bvA.z; oA.w = accA.w * inv + bvA.w;
    oB.x = accB.x * inv + bvB.x; oB.y = accB.y * inv + bvB.y;
    oB.z = accB.z * inv + bvB.z; oB.w = accB.w * inv + bvB.w;
    if (applyRelu) {
        oA.x = fmaxf(oA.x, 0.f); oA.y = fmaxf(oA.y, 0.f);
        oA.z = fmaxf(oA.z, 0.f); oA.w = fmaxf(oA.w, 0.f);
        oB.x = fmaxf(oB.x, 0.f); oB.y = fmaxf(oB.y, 0.f);
        oB.z = fmaxf(oB.z, 0.f); oB.w = fmaxf(oB.w, 0.f);
    }
    if (lane < 16) {
        ((float4*)out)[(size_t)node * 32 + qlane * 2] = oA;
        ((float4*)out)[(size_t)node * 32 + qlane * 2 + 1] = oB;
    }
}

// ---------------------------------------------------------------------------

extern "C" void kernel_launch(void* const* d_in, const int* in_sizes, int n_in,
                              void* d_out, int out_size, void* d_ws, size_t ws_size,
                              hipStream_t stream) {
    const float* x    = (const float*)d_in[0];
    const int* eidx   = (const int*)d_in[1];
    const float* Wl1  = (const float*)d_in[2];
    const float* bl1  = (const float*)d_in[3];
    const float* Wr1  = (const float*)d_in[4];
    const float* br1  = (const float*)d_in[5];
    const float* att1 = (const float*)d_in[6];
    const float* b1   = (const float*)d_in[7];
    const float* Wl2  = (const float*)d_in[8];
    const float* bl2  = (const float*)d_in[9];
    const float* Wr2  = (const float*)d_in[10];
    const float* br2  = (const float*)d_in[11];
    const float* att2 = (const float*)d_in[12];
    const float* b2   = (const float*)d_in[13];

    const int N = in_sizes[0] / 128;
    const int E = in_sizes[1] / 2;
    const int* src = eidx;
    const int* dst = eidx + E;

    const int nBlk = (N + 255) / 256;

    // workspace layout
    size_t NF = (size_t)N * 128;
    short* xl16 = (short*)d_ws;               // bf16 xl plane [N][128]
    float* bufB = (float*)(xl16 + NF);        // xr fp32
    float* bufC = bufB + NF;                  // h fp32 (layer-1 out)
    int* deg       = (int*)(bufC + NF);       // [N]
    int* row_ptr   = deg + N;                 // [N+1]
    int* writeidx  = row_ptr + (N + 1);       // [N]
    int* csr_src   = writeidx + N;            // [E]
    int* blockSums = csr_src + E;             // [nBlk]
    short* wt      = (short*)(blockSums + nBlk);  // 4 matrices x (hi+lo) x 16384

    float* outF = (float*)d_out;

    // --- CSR build + W prep (5 dispatches) ---
    const int nCnt = (E + 255) / 256;
    hipMemsetAsync(deg, 0, (size_t)N * sizeof(int), stream);
    count_prep_kernel<<<nCnt + 32, 256, 0, stream>>>(dst, deg, E, nCnt,
                                                     Wl1, Wr1, Wl2, Wr2, wt);
    scan_blocksum_kernel<<<nBlk, 256, 0, stream>>>(deg, blockSums, N);
    scan_apply2_kernel<<<nBlk, 256, 0, stream>>>(deg, blockSums, row_ptr, writeidx, N, nBlk);
    scatter_edges_kernel<<<nCnt, 256, 0, stream>>>(src, dst, writeidx, csr_src, E);

    dim3 gemmGrid((N + 63) / 64);
    dim3 aggGrid((N + 3) / 4);

    // --- layer 1 ---
    gemm_mfma_dual64_kernel<<<gemmGrid, 256, 0, stream>>>(x, wt, bl1, xl16, br1, bufB, N);
    gat_aggregate_kernel<<<aggGrid, 256, 0, stream>>>(xl16, bufB, att1, b1, row_ptr, csr_src,
                                                      bufC, N, 1);
    // --- layer 2 ---
    gemm_mfma_dual64_kernel<<<gemmGrid, 256, 0, stream>>>(bufC, wt + 2 * 2 * 16384, bl2, xl16,
                                                          br2, bufB, N);
    gat_aggregate_kernel<<<aggGrid, 256, 0, stream>>>(xl16, bufB, att2, b2, row_ptr, csr_src,
                                                      outF, N, 0);
}

// Round 9
// 295.505 us; speedup vs baseline: 2.2033x; 1.1411x over previous
//
#include <hip/hip_runtime.h>
#include <math.h>

// ---------------------------------------------------------------------------
// GATv2 2-layer GNN, fp32 in/out. N=50000, E=800000, F=128.
// 9 dispatches: memset -> count+prep_w (stores per-edge rank) -> scan_blocksum
//   -> scan_apply2 -> scatter (atomic-free, u16 csr) -> GEMM1 -> agg1 ->
//   GEMM2 -> agg2
// r8: xl stored bf16 RNE (gather bytes halved) -> 337us, absmax unchanged.
// r9: scatter de-pathologized: rank16 = return value of count's atomicAdd
//   (free), so scatter = row_ptr[dst]+rank16, no atomics, and csr entries are
//   u16 (src<65536) -> half the random-write lines (was 16x amplification,
//   52 MB for a 3.2 MB array).
// Falsified: grid.sync fusion (r5), split-operand GEMM (r4), agg SW-pipeline
//   (r1/r2), 1-block scan (r6).
// ---------------------------------------------------------------------------

typedef short bf16x8 __attribute__((ext_vector_type(8)));
typedef float f32x4 __attribute__((ext_vector_type(4)));

// ---------------------------------------------------------------------------
// count degrees + store rank (blocks [0,nCnt)) ; split W -> bf16 hi/lo
// [n][k] (last 32 blocks).
// ---------------------------------------------------------------------------
__global__ __launch_bounds__(256) void count_prep_kernel(
    const int* __restrict__ dst, int* __restrict__ deg,
    unsigned short* __restrict__ rank16, int E, int nCnt,
    const float* __restrict__ W0, const float* __restrict__ W1,
    const float* __restrict__ W2, const float* __restrict__ W3,
    short* __restrict__ wt) {
    if ((int)blockIdx.x < nCnt) {
        int i = blockIdx.x * 256 + threadIdx.x;
        if (i < E) {
            int r = atomicAdd(&deg[dst[i]], 1);
            rank16[i] = (unsigned short)r;
        }
    } else {
        int b = blockIdx.x - nCnt;           // 0..31
        int mat = b >> 3, chunk = b & 7;
        const float* W = (mat == 0) ? W0 : (mat == 1) ? W1 : (mat == 2) ? W2 : W3;
        short* hi = wt + (size_t)mat * 2 * 16384;
        short* lo = hi + 16384;
        int i0 = chunk * 2048;
        for (int i = i0 + threadIdx.x; i < i0 + 2048; i += 256) {
            int k = i >> 7, n = i & 127;
            float x = W[i];
            unsigned u = __float_as_uint(x);
            unsigned hu = u & 0xFFFF0000u;
            float lf = x - __uint_as_float(hu);
            hi[n * 128 + k] = (short)(hu >> 16);
            lo[n * 128 + k] = (short)(__float_as_uint(lf) >> 16);
        }
    }
}

// --- scan pass 1 -- per-block (256 nodes) sums ---
__global__ __launch_bounds__(256) void scan_blocksum_kernel(const int* __restrict__ deg,
                                                            int* __restrict__ blockSums, int n) {
    __shared__ int wsum[4];
    int tid = threadIdx.x;
    int idx = blockIdx.x * 256 + tid;
    int v = (idx < n) ? deg[idx] : 0;
    int lane = tid & 63, wid = tid >> 6;
    #pragma unroll
    for (int off = 32; off > 0; off >>= 1) v += __shfl_xor(v, off);
    if (lane == 0) wsum[wid] = v;
    __syncthreads();
    if (tid == 0) blockSums[blockIdx.x] = wsum[0] + wsum[1] + wsum[2] + wsum[3];
}

// --- scan pass 2 (fused): block offset by direct reduction over blockSums
//     (nBlk <= 256) + local scan -> row_ptr. Block 0 writes total.
__global__ __launch_bounds__(256) void scan_apply2_kernel(
    const int* __restrict__ deg, const int* __restrict__ blockSums,
    int* __restrict__ row_ptr, int n, int nBlk) {
    __shared__ int sPre[4], sAll[4], wsum[4];
    int tid = threadIdx.x, lane = tid & 63, wid = tid >> 6;

    int bsv = (tid < nBlk) ? blockSums[tid] : 0;
    int pre = (tid < (int)blockIdx.x) ? bsv : 0;
    int all = bsv;
    #pragma unroll
    for (int off = 32; off > 0; off >>= 1) {
        pre += __shfl_xor(pre, off);
        all += __shfl_xor(all, off);
    }
    if (lane == 0) { sPre[wid] = pre; sAll[wid] = all; }
    __syncthreads();
    int off0 = sPre[0] + sPre[1] + sPre[2] + sPre[3];
    int total = sAll[0] + sAll[1] + sAll[2] + sAll[3];

    int idx = blockIdx.x * 256 + tid;
    int v = (idx < n) ? deg[idx] : 0;
    int incl = v;
    #pragma unroll
    for (int off = 1; off < 64; off <<= 1) {
        int t = __shfl_up(incl, off);
        if (lane >= off) incl += t;
    }
    if (lane == 63) wsum[wid] = incl;
    __syncthreads();
    int woff = 0;
    #pragma unroll
    for (int w = 0; w < 4; ++w) woff += (w < wid) ? wsum[w] : 0;
    int excl = off0 + woff + (incl - v);
    if (idx < n) row_ptr[idx] = excl;
    if (blockIdx.x == 0 && tid == 0) row_ptr[n] = total;
}

// --- atomic-free scatter: pos = row_ptr[dst] + rank16, csr entry = u16 src ---
__global__ void scatter_edges_kernel(const int* __restrict__ src, const int* __restrict__ dst,
                                     const int* __restrict__ row_ptr,
                                     const unsigned short* __restrict__ rank16,
                                     unsigned short* __restrict__ csr16, int E) {
    int i = blockIdx.x * blockDim.x + threadIdx.x;
    if (i < E) {
        int d = dst[i];
        int pos = row_ptr[d] + (int)rank16[i];
        csr16[pos] = (unsigned short)src[i];
    }
}

// ---------------------------------------------------------------------------
// One-barrier split-bf16 MFMA GEMM, dual-output 64x256 tile:
//   xl-plane (p=0) -> bf16 RNE [Nrows][128]; xr-plane (p=1) -> fp32.
// Phase 1: stage full 64x128 A-tile, split -> Ahi/Alo LDS (stride 136).
// ONE __syncthreads. Phase 2: 4 K-chunks pure compute (B frags from L2).
// ---------------------------------------------------------------------------
#define LDK 136
__global__ __launch_bounds__(256) void gemm_mfma_dual64_kernel(
    const float* __restrict__ X, const short* __restrict__ wtL,
    const float* __restrict__ b0, short* __restrict__ out0bf,
    const float* __restrict__ b1, float* __restrict__ out1,
    int Nrows) {
    __shared__ __attribute__((aligned(16))) short Ahi[64][LDK];
    __shared__ __attribute__((aligned(16))) short Alo[64][LDK];

    int tid = threadIdx.x;
    int w = tid >> 6, lane = tid & 63, q = lane >> 4, tr = lane & 15;
    int m0 = blockIdx.x * 64;
    int n0 = w * 32;

    // --- phase 1: stage whole A tile, one row per thread-quad ---
    {
        int srow = tid >> 2;            // 0..63
        int c0 = (tid & 3) * 32;        // 0,32,64,96
        int gr = m0 + srow; if (gr >= Nrows) gr = Nrows - 1;  // stores guarded later
        const float* xp = &X[(size_t)gr * 128 + c0];
        float4 v[8];
        #pragma unroll
        for (int j = 0; j < 8; ++j) v[j] = *(const float4*)(xp + j * 4);
        #pragma unroll
        for (int j = 0; j < 4; ++j) {
            bf16x8 hv, lv;
            #pragma unroll
            for (int k = 0; k < 2; ++k) {
                float4 vv = v[j * 2 + k];
                float f[4] = {vv.x, vv.y, vv.z, vv.w};
                #pragma unroll
                for (int e = 0; e < 4; ++e) {
                    unsigned u = __float_as_uint(f[e]);
                    unsigned hu = u & 0xFFFF0000u;
                    float lf = f[e] - __uint_as_float(hu);
                    hv[k * 4 + e] = (short)(hu >> 16);
                    lv[k * 4 + e] = (short)(__float_as_uint(lf) >> 16);
                }
            }
            *(bf16x8*)&Ahi[srow][c0 + j * 8] = hv;
            *(bf16x8*)&Alo[srow][c0 + j * 8] = lv;
        }
    }
    __syncthreads();

    // --- phase 2: pure compute ---
    f32x4 acc[4][4];   // [mt][p*2+nt]
    #pragma unroll
    for (int a = 0; a < 4; ++a)
        #pragma unroll
        for (int b = 0; b < 4; ++b) acc[a][b] = (f32x4){0.f, 0.f, 0.f, 0.f};

    for (int kc = 0; kc < 128; kc += 32) {
        bf16x8 bh[4], bl[4];
        #pragma unroll
        for (int p = 0; p < 2; ++p) {
            const short* base = wtL + (size_t)p * 2 * 16384;
            #pragma unroll
            for (int nt = 0; nt < 2; ++nt) {
                size_t boff = (size_t)(n0 + nt * 16 + tr) * 128 + kc + q * 8;
                bh[p * 2 + nt] = *(const bf16x8*)&base[boff];
                bl[p * 2 + nt] = *(const bf16x8*)&base[16384 + boff];
            }
        }
        #pragma unroll
        for (int mt = 0; mt < 4; ++mt) {
            bf16x8 ah = *(const bf16x8*)&Ahi[mt * 16 + tr][kc + q * 8];
            bf16x8 al = *(const bf16x8*)&Alo[mt * 16 + tr][kc + q * 8];
            #pragma unroll
            for (int j = 0; j < 4; ++j) {
                acc[mt][j] = __builtin_amdgcn_mfma_f32_16x16x32_bf16(ah, bh[j], acc[mt][j], 0, 0, 0);
                acc[mt][j] = __builtin_amdgcn_mfma_f32_16x16x32_bf16(ah, bl[j], acc[mt][j], 0, 0, 0);
                acc[mt][j] = __builtin_amdgcn_mfma_f32_16x16x32_bf16(al, bh[j], acc[mt][j], 0, 0, 0);
            }
        }
    }

    // epilogue: D layout col = tr, row = q*4 + r
    // p=0 (xl): bf16 RNE store. p=1 (xr): fp32 store.
    #pragma unroll
    for (int nt = 0; nt < 2; ++nt) {
        float bv0 = b0[n0 + nt * 16 + tr];
        float bv1 = b1[n0 + nt * 16 + tr];
        #pragma unroll
        for (int mt = 0; mt < 4; ++mt) {
            #pragma unroll
            for (int r = 0; r < 4; ++r) {
                int row = m0 + mt * 16 + q * 4 + r;
                if (row < Nrows) {
                    float v0 = acc[mt][nt][r] + bv0;
                    unsigned u = __float_as_uint(v0);
                    unsigned rb = (u + 0x7FFFu + ((u >> 16) & 1u)) >> 16;
                    out0bf[(size_t)row * 128 + n0 + nt * 16 + tr] = (short)rb;
                    out1[(size_t)row * 128 + n0 + nt * 16 + tr] = acc[mt][2 + nt][r] + bv1;
                }
            }
        }
    }
}
#undef LDK

// ---------------------------------------------------------------------------
// Aggregation v6: xl is bf16 [N][128], csr entries u16. 16-lane groups,
// 4 edges/wave. Lane qlane holds features [qlane*8, qlane*8+8): ONE 16B load
// per edge-row. Per-edge reduce: 4 intra-16 shfl_xor (DPP). xor16/32 hoisted.
// ---------------------------------------------------------------------------
__global__ __launch_bounds__(256) void gat_aggregate_kernel(
    const short* __restrict__ xl16, const float* __restrict__ xr,
    const float* __restrict__ att, const float* __restrict__ bias,
    const int* __restrict__ row_ptr, const unsigned short* __restrict__ csr16,
    float* __restrict__ out, int N, int applyRelu) {
    int wid = threadIdx.x >> 6;      // 0..3 -> node within block
    int lane = threadIdx.x & 63;
    int qlane = lane & 15;
    int qid = lane >> 4;
    int node = blockIdx.x * 4 + wid;
    if (node >= N) return;

    const bf16x8* xlb = (const bf16x8*)xl16;   // row = 16 x bf16x8
    float4 xrA = ((const float4*)xr)[(size_t)node * 32 + qlane * 2];
    float4 xrB = ((const float4*)xr)[(size_t)node * 32 + qlane * 2 + 1];
    float4 atA = ((const float4*)att)[qlane * 2];
    float4 atB = ((const float4*)att)[qlane * 2 + 1];

    int beg = row_ptr[node];
    int end = row_ptr[node + 1];

    float dsum = 0.f;
    float4 accA = {0.f, 0.f, 0.f, 0.f};
    float4 accB = {0.f, 0.f, 0.f, 0.f};

    for (int cbase = beg; cbase < end; cbase += 64) {
        int cnt = end - cbase;
        if (cnt > 64) cnt = 64;
        int myidx = (lane < cnt) ? (int)csr16[cbase + lane] : 0;  // coalesced u16
        int nq = (cnt + 3) >> 2;                                  // quads of 4 edges

        for (int g = 0; g < nq; ++g) {
            int eidx = 4 * g + qid;
            int s = __shfl(myidx, eidx);
            bf16x8 mv = xlb[((size_t)s << 4) + qlane];
            float4 vA, vB;
            vA.x = __uint_as_float(((unsigned)(unsigned short)mv[0]) << 16);
            vA.y = __uint_as_float(((unsigned)(unsigned short)mv[1]) << 16);
            vA.z = __uint_as_float(((unsigned)(unsigned short)mv[2]) << 16);
            vA.w = __uint_as_float(((unsigned)(unsigned short)mv[3]) << 16);
            vB.x = __uint_as_float(((unsigned)(unsigned short)mv[4]) << 16);
            vB.y = __uint_as_float(((unsigned)(unsigned short)mv[5]) << 16);
            vB.z = __uint_as_float(((unsigned)(unsigned short)mv[6]) << 16);
            vB.w = __uint_as_float(((unsigned)(unsigned short)mv[7]) << 16);

            float t, p;
            t = vA.x + xrA.x; t = t > 0.f ? t : 0.2f * t; p = t * atA.x;
            t = vA.y + xrA.y; t = t > 0.f ? t : 0.2f * t; p = fmaf(t, atA.y, p);
            t = vA.z + xrA.z; t = t > 0.f ? t : 0.2f * t; p = fmaf(t, atA.z, p);
            t = vA.w + xrA.w; t = t > 0.f ? t : 0.2f * t; p = fmaf(t, atA.w, p);
            t = vB.x + xrB.x; t = t > 0.f ? t : 0.2f * t; p = fmaf(t, atB.x, p);
            t = vB.y + xrB.y; t = t > 0.f ? t : 0.2f * t; p = fmaf(t, atB.y, p);
            t = vB.z + xrB.z; t = t > 0.f ? t : 0.2f * t; p = fmaf(t, atB.z, p);
            t = vB.w + xrB.w; t = t > 0.f ? t : 0.2f * t; p = fmaf(t, atB.w, p);

            p += __shfl_xor(p, 1);
            p += __shfl_xor(p, 2);
            p += __shfl_xor(p, 4);
            p += __shfl_xor(p, 8);

            float e = (eidx < cnt) ? __expf(p) : 0.f;
            dsum += e;
            accA.x = fmaf(e, vA.x, accA.x);
            accA.y = fmaf(e, vA.y, accA.y);
            accA.z = fmaf(e, vA.z, accA.z);
            accA.w = fmaf(e, vA.w, accA.w);
            accB.x = fmaf(e, vB.x, accB.x);
            accB.y = fmaf(e, vB.y, accB.y);
            accB.z = fmaf(e, vB.z, accB.z);
            accB.w = fmaf(e, vB.w, accB.w);
        }
    }

    #pragma unroll
    for (int off = 16; off <= 32; off <<= 1) {
        dsum += __shfl_xor(dsum, off);
        accA.x += __shfl_xor(accA.x, off);
        accA.y += __shfl_xor(accA.y, off);
        accA.z += __shfl_xor(accA.z, off);
        accA.w += __shfl_xor(accA.w, off);
        accB.x += __shfl_xor(accB.x, off);
        accB.y += __shfl_xor(accB.y, off);
        accB.z += __shfl_xor(accB.z, off);
        accB.w += __shfl_xor(accB.w, off);
    }

    float inv = dsum > 0.f ? 1.f / dsum : 0.f;
    float4 bvA = ((const float4*)bias)[qlane * 2];
    float4 bvB = ((const float4*)bias)[qlane * 2 + 1];
    float4 oA, oB;
    oA.x = accA.x * inv + bvA.x; oA.y = accA.y * inv + bvA.y;
    oA.z = accA.z * inv + bvA.z; oA.w = accA.w * inv + bvA.w;
    oB.x = accB.x * inv + bvB.x; oB.y = accB.y * inv + bvB.y;
    oB.z = accB.z * inv + bvB.z; oB.w = accB.w * inv + bvB.w;
    if (applyRelu) {
        oA.x = fmaxf(oA.x, 0.f); oA.y = fmaxf(oA.y, 0.f);
        oA.z = fmaxf(oA.z, 0.f); oA.w = fmaxf(oA.w, 0.f);
        oB.x = fmaxf(oB.x, 0.f); oB.y = fmaxf(oB.y, 0.f);
        oB.z = fmaxf(oB.z, 0.f); oB.w = fmaxf(oB.w, 0.f);
    }
    if (lane < 16) {
        ((float4*)out)[(size_t)node * 32 + qlane * 2] = oA;
        ((float4*)out)[(size_t)node * 32 + qlane * 2 + 1] = oB;
    }
}

// ---------------------------------------------------------------------------

extern "C" void kernel_launch(void* const* d_in, const int* in_sizes, int n_in,
                              void* d_out, int out_size, void* d_ws, size_t ws_size,
                              hipStream_t stream) {
    const float* x    = (const float*)d_in[0];
    const int* eidx   = (const int*)d_in[1];
    const float* Wl1  = (const float*)d_in[2];
    const float* bl1  = (const float*)d_in[3];
    const float* Wr1  = (const float*)d_in[4];
    const float* br1  = (const float*)d_in[5];
    const float* att1 = (const float*)d_in[6];
    const float* b1   = (const float*)d_in[7];
    const float* Wl2  = (const float*)d_in[8];
    const float* bl2  = (const float*)d_in[9];
    const float* Wr2  = (const float*)d_in[10];
    const float* br2  = (const float*)d_in[11];
    const float* att2 = (const float*)d_in[12];
    const float* b2   = (const float*)d_in[13];

    const int N = in_sizes[0] / 128;
    const int E = in_sizes[1] / 2;
    const int* src = eidx;
    const int* dst = eidx + E;

    const int nBlk = (N + 255) / 256;

    // workspace layout
    size_t NF = (size_t)N * 128;
    short* xl16 = (short*)d_ws;               // bf16 xl plane [N][128]
    float* bufB = (float*)(xl16 + NF);        // xr fp32
    float* bufC = bufB + NF;                  // h fp32 (layer-1 out)
    int* deg       = (int*)(bufC + NF);       // [N]
    int* row_ptr   = deg + N;                 // [N+1]
    int* blockSums = row_ptr + (N + 1);       // [nBlk]
    unsigned short* rank16 = (unsigned short*)(blockSums + nBlk);  // [E]
    unsigned short* csr16  = rank16 + E;      // [E]
    short* wt      = (short*)(csr16 + E);     // 4 matrices x (hi+lo) x 16384

    float* outF = (float*)d_out;

    // --- CSR build + W prep (5 dispatches) ---
    const int nCnt = (E + 255) / 256;
    hipMemsetAsync(deg, 0, (size_t)N * sizeof(int), stream);
    count_prep_kernel<<<nCnt + 32, 256, 0, stream>>>(dst, deg, rank16, E, nCnt,
                                                     Wl1, Wr1, Wl2, Wr2, wt);
    scan_blocksum_kernel<<<nBlk, 256, 0, stream>>>(deg, blockSums, N);
    scan_apply2_kernel<<<nBlk, 256, 0, stream>>>(deg, blockSums, row_ptr, N, nBlk);
    scatter_edges_kernel<<<nCnt, 256, 0, stream>>>(src, dst, row_ptr, rank16, csr16, E);

    dim3 gemmGrid((N + 63) / 64);
    dim3 aggGrid((N + 3) / 4);

    // --- layer 1 ---
    gemm_mfma_dual64_kernel<<<gemmGrid, 256, 0, stream>>>(x, wt, bl1, xl16, br1, bufB, N);
    gat_aggregate_kernel<<<aggGrid, 256, 0, stream>>>(xl16, bufB, att1, b1, row_ptr, csr16,
                                                      bufC, N, 1);
    // --- layer 2 ---
    gemm_mfma_dual64_kernel<<<gemmGrid, 256, 0, stream>>>(bufC, wt + 2 * 2 * 16384, bl2, xl16,
                                                          br2, bufB, N);
    gat_aggregate_kernel<<<aggGrid, 256, 0, stream>>>(xl16, bufB, att2, b2, row_ptr, csr16,
                                                      outF, N, 0);
}